// Round 2
// baseline (844.193 us; speedup 1.0000x reference)
//
#include <hip/hip_runtime.h>
#include <hip/hip_bf16.h>

#define NTOK 49
#define DIMC 256

typedef __attribute__((ext_vector_type(8))) short bf16x8;
typedef __attribute__((ext_vector_type(4))) float f32x4;

__device__ __forceinline__ unsigned f2bf(float f) {
    union { float f; unsigned u; } v; v.f = f;
    return (v.u + 0x7FFFu + ((v.u >> 16) & 1u)) >> 16;
}

__global__ void convert_weights(const float* __restrict__ wq, const float* __restrict__ wp,
                                unsigned short* __restrict__ wqb, unsigned short* __restrict__ wpb) {
    int i = blockIdx.x * 256 + threadIdx.x;
    if (i < 768 * 256) wqb[i] = (unsigned short)f2bf(wq[i]);
    if (i < 256 * 256) wpb[i] = (unsigned short)f2bf(wp[i]);
}

// One window (49 tokens) per block. 8 waves = 512 threads.
// LDS map. Swizzle rule: XOR pattern must stay < row length (bijective in-row).
//   rows >=128B: XOR ((row&7)<<4)   rows ==64B: XOR ((row&3)<<4)
//   xb  [0,32768)      : x bf16, 64 rows x 512B   -> later: per-wave P staging (wid*4096, [64 q][32 key] bf16, 64B rows)
//   qb  [32768,65536)  : q [8][64 t][32 d] bf16 (64B rows) -> later: attn_out [64 t][256 d] bf16 (512B rows)
//   kb  [65536,98304)  : k [8][64 t][32 d] bf16 (64B rows)
//   vtb [98304,131072) : v^T [8][32 d][64 t] bf16 (128B rows)
//   mb  [131072,147456): mask f32 [64 q][64 key] (256B rows)
__launch_bounds__(512, 2)
__global__ void win_attn_fused(const float* __restrict__ x, const float* __restrict__ mask,
                               const unsigned short* __restrict__ wqb, const float* __restrict__ bqkv,
                               const unsigned short* __restrict__ wpb, const float* __restrict__ bproj,
                               float* __restrict__ out) {
    __shared__ __align__(16) char lds[147456];
    char* const xb  = lds;
    char* const qb  = lds + 32768;
    char* const kb  = lds + 65536;
    char* const vtb = lds + 98304;
    char* const mb  = lds + 131072;

    const int b = blockIdx.x;
    const int tid = threadIdx.x;
    const int lane = tid & 63;
    const int wid = tid >> 6;
    const int c = lane & 15;   // fragment row/col selector
    const int g = lane >> 4;   // k-group 0..3

    const f32x4 fzero = {0.f, 0.f, 0.f, 0.f};

    // ---------- phase 0: stage x (bf16) and mask (f32) ----------
    {
        const float* xw = x + (size_t)b * (NTOK * DIMC);
        #pragma unroll
        for (int it = 0; it < 8; ++it) {
            int idx = it * 512 + tid;         // 4096 quads of 4 floats
            int t = idx >> 6;
            int d0 = (idx & 63) * 4;
            float4 v = make_float4(0.f, 0.f, 0.f, 0.f);
            if (t < NTOK) v = *(const float4*)(xw + t * DIMC + d0);
            unsigned lo = f2bf(v.x) | (f2bf(v.y) << 16);
            unsigned hi = f2bf(v.z) | (f2bf(v.w) << 16);
            *(uint2*)(xb + t * 512 + ((d0 * 2) ^ ((t & 7) << 4))) = make_uint2(lo, hi);
        }
        const float* mw = mask + (size_t)b * (NTOK * NTOK);
        #pragma unroll
        for (int it = 0; it < 8; ++it) {
            int idx = it * 512 + tid;         // 4096 mask slots
            int q = idx >> 6;
            int key = idx & 63;
            float v;
            if (q < NTOK && key < NTOK) v = mw[q * NTOK + key];
            else v = (key >= NTOK) ? -1e30f : 0.f;
            *(float*)(mb + q * 256 + ((key * 4) ^ ((q & 7) << 4))) = v;
        }
    }
    __syncthreads();

    // ---------- phase 1: QKV GEMM (M=64, N=768, K=256) ----------
    {
        f32x4 acc[6][4];
        #pragma unroll
        for (int j = 0; j < 6; ++j)
            #pragma unroll
            for (int mt = 0; mt < 4; ++mt)
                acc[j][mt] = fzero;

        #pragma unroll
        for (int ks = 0; ks < 8; ++ks) {
            const int kk = ks * 32 + g * 8;
            bf16x8 af[4];
            #pragma unroll
            for (int mt = 0; mt < 4; ++mt) {
                int t = mt * 16 + c;
                af[mt] = *(const bf16x8*)(xb + t * 512 + ((kk * 2) ^ ((t & 7) << 4)));
            }
            #pragma unroll
            for (int j = 0; j < 6; ++j) {
                int o = (wid + 8 * j) * 16 + c;
                bf16x8 bfr = *(const bf16x8*)(wqb + (size_t)o * 256 + kk);
                #pragma unroll
                for (int mt = 0; mt < 4; ++mt)
                    acc[j][mt] = __builtin_amdgcn_mfma_f32_16x16x32_bf16(af[mt], bfr, acc[j][mt], 0, 0, 0);
            }
        }

        // scatter C tiles to q/k/vt LDS (+bias, ->bf16)
        #pragma unroll
        for (int j = 0; j < 6; ++j) {
            int nt = wid + 8 * j;
            int o = nt * 16 + c;
            float bias = bqkv[o];
            int sec = o >> 8;          // 0=q 1=k 2=v (wave-uniform per j)
            int oo = o & 255;
            int h = oo >> 5;
            int d = oo & 31;
            #pragma unroll
            for (int mt = 0; mt < 4; ++mt) {
                int t0 = mt * 16 + g * 4;
                f32x4 v = acc[j][mt];
                if (sec == 2) {
                    unsigned lo = f2bf(v[0] + bias) | (f2bf(v[1] + bias) << 16);
                    unsigned hi = f2bf(v[2] + bias) | (f2bf(v[3] + bias) << 16);
                    *(uint2*)(vtb + h * 4096 + d * 128 + ((t0 * 2) ^ ((d & 7) << 4))) = make_uint2(lo, hi);
                } else {
                    char* base = (sec == 0) ? qb : kb;
                    #pragma unroll
                    for (int r = 0; r < 4; ++r) {
                        int t = t0 + r;
                        *(unsigned short*)(base + h * 4096 + t * 64 + ((d * 2) ^ ((t & 3) << 4))) =
                            (unsigned short)f2bf(v[r] + bias);
                    }
                }
            }
        }
    }
    __syncthreads();

    // ---------- phase 2: attention, wave = head ----------
    f32x4 oacc[2][4];
    {
        const int h = wid;
        bf16x8 kf[4], qf[4];
        #pragma unroll
        for (int it = 0; it < 4; ++it) {
            int key = it * 16 + c;
            kf[it] = *(const bf16x8*)(kb + h * 4096 + key * 64 + ((g * 16) ^ ((key & 3) << 4)));
        }
        #pragma unroll
        for (int jt = 0; jt < 4; ++jt) {
            int q = jt * 16 + c;
            qf[jt] = *(const bf16x8*)(qb + h * 4096 + q * 64 + ((g * 16) ^ ((q & 3) << 4)));
        }
        // S^T = K·Q^T : C col = q (lane&15), row = key ((lane>>4)*4+r)
        float p[4][4][4];
        const float scale = 0.17677669529663687f;  // 32^-0.5
        #pragma unroll
        for (int it = 0; it < 4; ++it) {
            #pragma unroll
            for (int jt = 0; jt < 4; ++jt) {
                f32x4 s = __builtin_amdgcn_mfma_f32_16x16x32_bf16(kf[it], qf[jt], fzero, 0, 0, 0);
                int q = jt * 16 + c;
                int key0 = it * 16 + g * 4;
                f32x4 mv = *(const f32x4*)(mb + q * 256 + ((key0 * 4) ^ ((q & 7) << 4)));
                #pragma unroll
                for (int r = 0; r < 4; ++r)
                    p[it][jt][r] = fmaf(s[r], scale, mv[r]);
            }
        }
        // softmax over keys; lanes {c,c+16,c+32,c+48} share a query column
        #pragma unroll
        for (int jt = 0; jt < 4; ++jt) {
            float m = -1e30f;
            #pragma unroll
            for (int it = 0; it < 4; ++it)
                #pragma unroll
                for (int r = 0; r < 4; ++r)
                    m = fmaxf(m, p[it][jt][r]);
            m = fmaxf(m, __shfl_xor(m, 16));
            m = fmaxf(m, __shfl_xor(m, 32));
            float ssum = 0.f;
            #pragma unroll
            for (int it = 0; it < 4; ++it)
                #pragma unroll
                for (int r = 0; r < 4; ++r) {
                    float e = __expf(p[it][jt][r] - m);
                    p[it][jt][r] = e;
                    ssum += e;
                }
            ssum += __shfl_xor(ssum, 16);
            ssum += __shfl_xor(ssum, 32);
            float inv = 1.0f / ssum;
            #pragma unroll
            for (int it = 0; it < 4; ++it)
                #pragma unroll
                for (int r = 0; r < 4; ++r)
                    p[it][jt][r] *= inv;
        }
        // PV: out^T = V^T · P^T, P bounced through private LDS slice in 2 key-halves
        char* const pl = xb + wid * 4096;   // [64 q][32 keyh] bf16, 64B rows
        #pragma unroll
        for (int dt = 0; dt < 2; ++dt)
            #pragma unroll
            for (int jt = 0; jt < 4; ++jt)
                oacc[dt][jt] = fzero;

        #pragma unroll
        for (int kh = 0; kh < 2; ++kh) {
            #pragma unroll
            for (int it2 = 0; it2 < 2; ++it2) {
                int it = kh * 2 + it2;
                #pragma unroll
                for (int jt = 0; jt < 4; ++jt) {
                    int q = jt * 16 + c;
                    int keyh = it2 * 16 + g * 4;
                    unsigned lo = f2bf(p[it][jt][0]) | (f2bf(p[it][jt][1]) << 16);
                    unsigned hi = f2bf(p[it][jt][2]) | (f2bf(p[it][jt][3]) << 16);
                    *(uint2*)(pl + q * 64 + ((keyh * 2) ^ ((q & 3) << 4))) = make_uint2(lo, hi);
                }
            }
            bf16x8 vf[2];
            #pragma unroll
            for (int dt = 0; dt < 2; ++dt) {
                int d = dt * 16 + c;
                vf[dt] = *(const bf16x8*)(vtb + h * 4096 + d * 128 +
                                          (((kh * 32 + g * 8) * 2) ^ ((d & 7) << 4)));
            }
            #pragma unroll
            for (int jt = 0; jt < 4; ++jt) {
                int q = jt * 16 + c;
                bf16x8 pf = *(const bf16x8*)(pl + q * 64 + ((g * 16) ^ ((q & 3) << 4)));
                #pragma unroll
                for (int dt = 0; dt < 2; ++dt)
                    oacc[dt][jt] = __builtin_amdgcn_mfma_f32_16x16x32_bf16(vf[dt], pf, oacc[dt][jt], 0, 0, 0);
            }
        }
    }
    __syncthreads();   // all q/k LDS reads complete -> qb reusable as attn_out

    // attn_out -> qb region as [64 t][256 d] bf16, 512B rows
    {
        const int h = wid;
        #pragma unroll
        for (int dt = 0; dt < 2; ++dt) {
            #pragma unroll
            for (int jt = 0; jt < 4; ++jt) {
                int q = jt * 16 + c;
                int dg0 = h * 32 + dt * 16 + g * 4;
                f32x4 v = oacc[dt][jt];
                unsigned lo = f2bf(v[0]) | (f2bf(v[1]) << 16);
                unsigned hi = f2bf(v[2]) | (f2bf(v[3]) << 16);
                *(uint2*)(qb + q * 512 + ((dg0 * 2) ^ ((q & 7) << 4))) = make_uint2(lo, hi);
            }
        }
    }
    __syncthreads();

    // ---------- phase 3: proj GEMM (M=64, N=256, K=256) + bias ----------
    {
        f32x4 pacc[2][4];
        #pragma unroll
        for (int j = 0; j < 2; ++j)
            #pragma unroll
            for (int mt = 0; mt < 4; ++mt)
                pacc[j][mt] = fzero;

        #pragma unroll
        for (int ks = 0; ks < 8; ++ks) {
            int kk = ks * 32 + g * 8;
            bf16x8 af[4];
            #pragma unroll
            for (int mt = 0; mt < 4; ++mt) {
                int t = mt * 16 + c;
                af[mt] = *(const bf16x8*)(qb + t * 512 + ((kk * 2) ^ ((t & 7) << 4)));
            }
            #pragma unroll
            for (int j = 0; j < 2; ++j) {
                int o = (wid * 2 + j) * 16 + c;
                bf16x8 bfr = *(const bf16x8*)(wpb + (size_t)o * 256 + kk);
                #pragma unroll
                for (int mt = 0; mt < 4; ++mt)
                    pacc[j][mt] = __builtin_amdgcn_mfma_f32_16x16x32_bf16(af[mt], bfr, pacc[j][mt], 0, 0, 0);
            }
        }
        float* ob = out + (size_t)b * (NTOK * DIMC);
        #pragma unroll
        for (int j = 0; j < 2; ++j) {
            int o = (wid * 2 + j) * 16 + c;
            float bias = bproj[o];
            #pragma unroll
            for (int mt = 0; mt < 4; ++mt) {
                #pragma unroll
                for (int r = 0; r < 4; ++r) {
                    int t = mt * 16 + g * 4 + r;
                    if (t < NTOK) ob[t * DIMC + o] = pacc[j][mt][r] + bias;
                }
            }
        }
    }
}

extern "C" void kernel_launch(void* const* d_in, const int* in_sizes, int n_in,
                              void* d_out, int out_size, void* d_ws, size_t ws_size,
                              hipStream_t stream) {
    const float* x    = (const float*)d_in[0];
    const float* mask = (const float*)d_in[1];
    const float* wq   = (const float*)d_in[2];
    const float* bq   = (const float*)d_in[3];
    const float* wp   = (const float*)d_in[4];
    const float* bp   = (const float*)d_in[5];
    float* o = (float*)d_out;

    unsigned short* wqb = (unsigned short*)d_ws;          // 768*256 bf16
    unsigned short* wpb = wqb + 768 * 256;                // 256*256 bf16

    convert_weights<<<768, 256, 0, stream>>>(wq, wp, wqb, wpb);
    win_attn_fused<<<8192, 512, 0, stream>>>(x, mask, wqb, bq, wpb, bp, o);
}